// Round 10
// baseline (250.314 us; speedup 1.0000x reference)
//
#include <hip/hip_runtime.h>
#include <stdint.h>

typedef signed char i8;
typedef __attribute__((ext_vector_type(4))) float f32x4;
typedef __attribute__((ext_vector_type(4))) int i32x4;

#define XSCALE 32.0f
#define INV_XSCALE (1.0f / 32.0f)

// ---------------- conversion kernels ----------------

__device__ __forceinline__ int q8(float f) {
  float s = rintf(f * XSCALE);
  s = fminf(fmaxf(s, -127.0f), 127.0f);
  return ((int)s) & 0xff;
}

// x fp32 -> i8 (scale 32), 16 elems/thread
__global__ __launch_bounds__(256) void cvt_x_kernel(const float* __restrict__ x,
                                                    i32x4* __restrict__ o, int n16) {
  int i = blockIdx.x * blockDim.x + threadIdx.x;
  int stride = gridDim.x * blockDim.x;
  for (; i < n16; i += stride) {
    const f32x4* p = (const f32x4*)x + (size_t)i * 4;
    f32x4 v0 = p[0], v1 = p[1], v2 = p[2], v3 = p[3];
    i32x4 r;
    r[0] = q8(v0[0]) | (q8(v0[1]) << 8) | (q8(v0[2]) << 16) | (q8(v0[3]) << 24);
    r[1] = q8(v1[0]) | (q8(v1[1]) << 8) | (q8(v1[2]) << 16) | (q8(v1[3]) << 24);
    r[2] = q8(v2[0]) | (q8(v2[1]) << 8) | (q8(v2[2]) << 16) | (q8(v2[3]) << 24);
    r[3] = q8(v3[0]) | (q8(v3[1]) << 8) | (q8(v3[2]) << 16) | (q8(v3[3]) << 24);
    o[i] = r;
  }
}

__device__ __forceinline__ int sg8(float f) {
  return (f > 0.0f ? 1 : (f < 0.0f ? -1 : 0)) & 0xff;
}

// w fp32 -> sign i8 (+1/-1/0), 16 elems/thread
__global__ __launch_bounds__(256) void cvt_w_kernel(const float* __restrict__ w,
                                                    i32x4* __restrict__ o, int n16) {
  int i = blockIdx.x * blockDim.x + threadIdx.x;
  int stride = gridDim.x * blockDim.x;
  for (; i < n16; i += stride) {
    const f32x4* p = (const f32x4*)w + (size_t)i * 4;
    f32x4 v0 = p[0], v1 = p[1], v2 = p[2], v3 = p[3];
    i32x4 r;
    r[0] = sg8(v0[0]) | (sg8(v0[1]) << 8) | (sg8(v0[2]) << 16) | (sg8(v0[3]) << 24);
    r[1] = sg8(v1[0]) | (sg8(v1[1]) << 8) | (sg8(v1[2]) << 16) | (sg8(v1[3]) << 24);
    r[2] = sg8(v2[0]) | (sg8(v2[1]) << 8) | (sg8(v2[2]) << 16) | (sg8(v2[3]) << 24);
    r[3] = sg8(v3[0]) | (sg8(v3[1]) << 8) | (sg8(v3[2]) << 16) | (sg8(v3[3]) << 24);
    o[i] = r;
  }
}

// ---------------- 256x128 i8 GEMM: A via LDS, B via vmem gather -----------
// r23 = r22 with the rotation-parity BUG fixed. r22 rotated LDS buffers
// period-3 but B registers period-2 inside an unroll-3 loop: tile t+3
// consumed Bb0 holding stale B(t+2) -> absmax 278. Fix: unroll by
// LCM(3,2)=6 with static (buffer, register) pairing; tile t always uses
// Bb[t%2], gathered at t-1 into Bb[t%2]. Everything else identical:
//  - B off LDS onto the idle vmem/L1 path (16 fully-consumed 64B lines
//    per gather instr); B(t+1) issued a full tile (~1400cyc) ahead;
//  - counted vmcnt: pre-MFMA retire B(t) via VMCNT12 (steady state),
//    pre-BAR retire SA(t+1) via VMCNT8 -- never 0 in steady state;
//    (ledger is order-robust: after VMCNT8 only this tile's 8 issues
//    remain outstanding, so all prior-tile ops are retired.)
//  - LDS-port demand: A-read(amp2)+A-stage = 131k cyc/CU < MFMA 167k;
//  - 2 co-resident 4-wave blocks (256 thr, block 256x128, wave 128x64),
//    A-only LDS 3 x 16KB = 48KB/block.

__device__ __forceinline__ void load_lds16(const void* g, void* l) {
  __builtin_amdgcn_global_load_lds(
      (const __attribute__((address_space(1))) void*)g,
      (__attribute__((address_space(3))) void*)l,
      16, 0, 0);
}

// stage one 4KB unit (64 rows x 64 cols i8) with 4 waves x 1KB; u=0..3.
__device__ __forceinline__ void stage_u4(const i8* __restrict__ Gp, int K, int k0,
                                         i8* __restrict__ Tlds, int u, int wave,
                                         int lane) {
  const int base = u * 4096 + wave * 1024;        // physical byte base (wave-uniform)
  const int PA = base + lane * 16;                // this lane's physical bytes
  const int L = PA ^ (((PA >> 7) & 3) << 4);      // logical bytes (involution)
  const int r = L >> 6;                           // tile row (64 i8 per row)
  const int c = L & 63;                           // tile col (16-aligned)
  load_lds16(Gp + (size_t)r * K + k0 + c, Tlds + base);
}

#define BAR __builtin_amdgcn_s_barrier()
#define SGB __builtin_amdgcn_sched_barrier(0)
#define WAITL0 asm volatile("s_waitcnt lgkmcnt(0)" ::: "memory")
#define VMCNT12 asm volatile("s_waitcnt vmcnt(12)" ::: "memory")
#define VMCNT8 asm volatile("s_waitcnt vmcnt(8)" ::: "memory")
#define VMCNT4 asm volatile("s_waitcnt vmcnt(4)" ::: "memory")
#define VMCNT0 asm volatile("s_waitcnt vmcnt(0)" ::: "memory")

#define MFMA32(BS)                                                              \
  __builtin_amdgcn_s_setprio(1);                                                \
  _Pragma("unroll") for (int mi = 0; mi < 8; ++mi)                              \
  _Pragma("unroll") for (int ni = 0; ni < 4; ++ni)                              \
    acc[mi][ni] = __builtin_amdgcn_mfma_i32_16x16x64_i8(                        \
        Af[mi], BS[ni], acc[mi][ni], 0, 0, 0);                                  \
  __builtin_amdgcn_s_setprio(0);

// PR = A buf[t%3] (read), PS = A buf[(t+2)%3] (stage target, tile t+2).
// BCUR = B(t) regs (gathered during t-1), BNXT <- B(t+1) from global.
#define DO_TILE(t, PR, PS, BCUR, BNXT)                                          \
  if ((t) < NT) {                                                               \
    if ((t) + 1 < NT) {                                                         \
      _Pragma("unroll") for (int ni = 0; ni < 4; ++ni)                          \
        BNXT[ni] = *(const i32x4*)(GBrow[ni] + (size_t)((t) + 1) * 64);         \
    }                                                                           \
    if ((t) + 2 < NT) {                                                         \
      const int k2 = ((t) + 2) * 64;                                            \
      stage_u4(GA, K, k2, (PS), 0, wave, lane);                                 \
      stage_u4(GA, K, k2, (PS), 1, wave, lane);                                 \
      stage_u4(GA, K, k2, (PS), 2, wave, lane);                                 \
      stage_u4(GA, K, k2, (PS), 3, wave, lane);                                 \
    }                                                                           \
    _Pragma("unroll") for (int mi = 0; mi < 8; ++mi)                            \
      Af[mi] = *(const i32x4*)((PR) + abase + mi * 1024);                       \
    WAITL0;                                       /* A frags ready */           \
    if ((t) + 2 < NT) { VMCNT12; }                /* B(t) ready */              \
    else if ((t) + 1 < NT) { VMCNT8; }                                          \
    else { VMCNT0; }                                                            \
    SGB;                                                                        \
    MFMA32(BCUR);                                                               \
    SGB;                                                                        \
    if ((t) + 2 < NT) { VMCNT8; }                 /* SA(t+1) landed */          \
    else if ((t) + 1 < NT) { VMCNT4; }                                          \
    BAR;                                          /* publish SA(t+1) */         \
  }

__global__ __launch_bounds__(256, 2) void bingemm128_kernel(
    const i8* __restrict__ A,      // [M][K] i8 (x * 32)
    const i8* __restrict__ B,      // [N][K] i8 sign
    const float* __restrict__ alpha,
    const float* __restrict__ bias,
    float* __restrict__ C,         // [M][N] fp32
    int M, int N, int K) {
  __shared__ i8 SM[3][16384];      // 3 x A-tile [256][64] = 48 KB

  const int tid = threadIdx.x;
  const int lane = tid & 63;
  const int wave = tid >> 6;  // 0..3
  const int wm = wave >> 1;   // 0..1 (128-row slab)
  const int wn = wave & 1;    // 0..1 (64-col slab)
  const int l15 = lane & 15;

  // XCD-aware swizzle (grid divisible by 8 -> simple bijection)
  const int nwg = gridDim.x;
  const int wg = blockIdx.x;
  const int wgid = ((nwg & 7) == 0) ? ((wg & 7) * (nwg >> 3) + (wg >> 3)) : wg;

  const int nbn = N / 128;
  const int tm = wgid / nbn;
  const int tn = wgid % nbn;

  const i8* GA = A + (size_t)tm * 256 * K;
  const i8* GB = B + (size_t)tn * 128 * K;

  // swizzled ds_read byte offsets for A (row stride 64B, granule 16B):
  // phys k-part = (kq ^ ((row>>1)&3))<<4, (row>>1)&3 == (l15>>1)&3
  const int kq = lane >> 4;                 // 0..3
  const int kph = ((kq ^ ((l15 >> 1) & 3)) << 4);
  const int abase = (wm * 128 + l15) * 64 + kph;   // + mi*1024 (16 rows)

  // B fragment global rows: frag ni = 16B at row (wn*64 + ni*16 + l15),
  // chunk kq*16, byte offset t*64. Lanes {l15+16k} cover 4x16B of one
  // 64B-line-per-row -> 16 fully-consumed lines per gather instruction.
  const i8* GBrow[4];
#pragma unroll
  for (int ni = 0; ni < 4; ++ni)
    GBrow[ni] = GB + (size_t)(wn * 64 + ni * 16 + l15) * K + kq * 16;

  i32x4 acc[8][4];
#pragma unroll
  for (int i = 0; i < 8; ++i)
#pragma unroll
    for (int j = 0; j < 4; ++j)
#pragma unroll
      for (int q = 0; q < 4; ++q) acc[i][j][q] = 0;

  const int NT = K / 64;

  i32x4 Af[8], Bb0[4], Bb1[4];

  i8* const q0 = &SM[0][0];
  i8* const q1 = &SM[1][0];
  i8* const q2 = &SM[2][0];

  // ---- prologue: gather B(0) first, then stage A(0)->q0, A(1)->q1;
  // retire B(0)+SA(0) together (order-robust: VMCNT4 leaves only SA(1)). --
#pragma unroll
  for (int ni = 0; ni < 4; ++ni)
    Bb0[ni] = *(const i32x4*)(GBrow[ni]);
  stage_u4(GA, K, 0, q0, 0, wave, lane);
  stage_u4(GA, K, 0, q0, 1, wave, lane);
  stage_u4(GA, K, 0, q0, 2, wave, lane);
  stage_u4(GA, K, 0, q0, 3, wave, lane);
  stage_u4(GA, K, 64, q1, 0, wave, lane);
  stage_u4(GA, K, 64, q1, 1, wave, lane);
  stage_u4(GA, K, 64, q1, 2, wave, lane);
  stage_u4(GA, K, 64, q1, 3, wave, lane);
  VMCNT4;   // retires B(0) and SA(0); SA(1) in flight
  BAR;

  // unroll 6 = LCM(buffer period 3, register period 2): tile t reads
  // q[t%3] and consumes Bb[t%2] -- parity-consistent across groups.
  for (int t = 0; t < NT; t += 6) {
    DO_TILE(t,     q0, q2, Bb0, Bb1);
    DO_TILE(t + 1, q1, q0, Bb1, Bb0);
    DO_TILE(t + 2, q2, q1, Bb0, Bb1);
    DO_TILE(t + 3, q0, q2, Bb1, Bb0);
    DO_TILE(t + 4, q1, q0, Bb0, Bb1);
    DO_TILE(t + 5, q2, q1, Bb1, Bb0);
  }

  // ---- epilogue: C = acc * alpha[col]/32 + bias[col] (nontemporal) ----
  const int r0 = tm * 256 + wm * 128 + ((lane >> 4) << 2);
  const int c0 = tn * 128 + wn * 64 + l15;
#pragma unroll
  for (int an = 0; an < 4; ++an) {
    const int col = c0 + an * 16;
    const float al = alpha[col] * INV_XSCALE;
    const float bi = bias[col];
#pragma unroll
    for (int am = 0; am < 8; ++am) {
#pragma unroll
      for (int j = 0; j < 4; ++j) {
        __builtin_nontemporal_store((float)acc[am][an][j] * al + bi,
                                    &C[(size_t)(r0 + am * 16 + j) * N + col]);
      }
    }
  }
}

// ---------------- fallback (insurance: ws too small / bad dims) ----------------

__global__ __launch_bounds__(256) void naive_kernel(
    const float* __restrict__ x, const float* __restrict__ w,
    const float* __restrict__ alpha, const float* __restrict__ bias,
    float* __restrict__ out, int M, int N, int K) {
  long idx = (long)blockIdx.x * blockDim.x + threadIdx.x;
  const long total = (long)M * N;
  const long stride = (long)gridDim.x * blockDim.x;
  for (; idx < total; idx += stride) {
    const int m = (int)(idx / N);
    const int n = (int)(idx % N);
    const float* xr = x + (size_t)m * K;
    const float* wr = w + (size_t)n * K;
    float s = 0.0f;
    for (int k = 0; k < K; ++k) {
      const float wv = wr[k];
      const float sg = (wv > 0.0f) ? 1.0f : ((wv < 0.0f) ? -1.0f : 0.0f);
      s += xr[k] * sg;
    }
    out[idx] = s * alpha[n] + bias[n];
  }
}

// ---------------- launcher ----------------

extern "C" void kernel_launch(void* const* d_in, const int* in_sizes, int n_in,
                              void* d_out, int out_size, void* d_ws, size_t ws_size,
                              hipStream_t stream) {
  const float* x = (const float*)d_in[0];
  const float* w = (const float*)d_in[1];
  const float* alpha = (const float*)d_in[2];
  const float* bias = (const float*)d_in[3];
  float* out = (float*)d_out;

  const int OUT = in_sizes[3];                // bias length
  const int IN = in_sizes[1] / OUT;           // weight is [OUT][IN]
  const int M = in_sizes[0] / IN;             // x is [B][IN]
  const int N = OUT, K = IN;

  const size_t xbytes = (size_t)M * K;        // i8
  const size_t wbytes = (size_t)N * K;        // i8
  // guards assume NT = K/64 >= 3.
  const bool ok = (ws_size >= xbytes + wbytes) &&
                  (M % 256 == 0) && (N % 128 == 0) && (K % 64 == 0) &&
                  (K >= 192);

  if (!ok) {
    naive_kernel<<<2048, 256, 0, stream>>>(x, w, alpha, bias, out, M, N, K);
    return;
  }

  i8* xb = (i8*)d_ws;
  i8* wb = xb + xbytes;

  cvt_x_kernel<<<2048, 256, 0, stream>>>(x, (i32x4*)xb, (int)((size_t)M * K / 16));
  cvt_w_kernel<<<2048, 256, 0, stream>>>(w, (i32x4*)wb, (int)((size_t)N * K / 16));

  const int grid = (M / 256) * (N / 128);
  bingemm128_kernel<<<grid, 256, 0, stream>>>(xb, wb, alpha, bias, out, M, N, K);
}

// Round 11
// 177.872 us; speedup vs baseline: 1.4073x; 1.4073x over previous
//
#include <hip/hip_runtime.h>
#include <stdint.h>

typedef signed char i8;
typedef __attribute__((ext_vector_type(4))) float f32x4;
typedef __attribute__((ext_vector_type(4))) int i32x4;

#define XSCALE 32.0f
#define INV_XSCALE (1.0f / 32.0f)

// ---------------- conversion kernels ----------------

__device__ __forceinline__ int q8(float f) {
  float s = rintf(f * XSCALE);
  s = fminf(fmaxf(s, -127.0f), 127.0f);
  return ((int)s) & 0xff;
}

// x fp32 -> i8 (scale 32), 16 elems/thread
__global__ __launch_bounds__(256) void cvt_x_kernel(const float* __restrict__ x,
                                                    i32x4* __restrict__ o, int n16) {
  int i = blockIdx.x * blockDim.x + threadIdx.x;
  int stride = gridDim.x * blockDim.x;
  for (; i < n16; i += stride) {
    const f32x4* p = (const f32x4*)x + (size_t)i * 4;
    f32x4 v0 = p[0], v1 = p[1], v2 = p[2], v3 = p[3];
    i32x4 r;
    r[0] = q8(v0[0]) | (q8(v0[1]) << 8) | (q8(v0[2]) << 16) | (q8(v0[3]) << 24);
    r[1] = q8(v1[0]) | (q8(v1[1]) << 8) | (q8(v1[2]) << 16) | (q8(v1[3]) << 24);
    r[2] = q8(v2[0]) | (q8(v2[1]) << 8) | (q8(v2[2]) << 16) | (q8(v2[3]) << 24);
    r[3] = q8(v3[0]) | (q8(v3[1]) << 8) | (q8(v3[2]) << 16) | (q8(v3[3]) << 24);
    o[i] = r;
  }
}

__device__ __forceinline__ int sg8(float f) {
  return (f > 0.0f ? 1 : (f < 0.0f ? -1 : 0)) & 0xff;
}

// w fp32 -> sign i8 (+1/-1/0), 16 elems/thread
__global__ __launch_bounds__(256) void cvt_w_kernel(const float* __restrict__ w,
                                                    i32x4* __restrict__ o, int n16) {
  int i = blockIdx.x * blockDim.x + threadIdx.x;
  int stride = gridDim.x * blockDim.x;
  for (; i < n16; i += stride) {
    const f32x4* p = (const f32x4*)w + (size_t)i * 4;
    f32x4 v0 = p[0], v1 = p[1], v2 = p[2], v3 = p[3];
    i32x4 r;
    r[0] = sg8(v0[0]) | (sg8(v0[1]) << 8) | (sg8(v0[2]) << 16) | (sg8(v0[3]) << 24);
    r[1] = sg8(v1[0]) | (sg8(v1[1]) << 8) | (sg8(v1[2]) << 16) | (sg8(v1[3]) << 24);
    r[2] = sg8(v2[0]) | (sg8(v2[1]) << 8) | (sg8(v2[2]) << 16) | (sg8(v2[3]) << 24);
    r[3] = sg8(v3[0]) | (sg8(v3[1]) << 8) | (sg8(v3[2]) << 16) | (sg8(v3[3]) << 24);
    o[i] = r;
  }
}

// ---------------- 256x256 i8 GEMM, ring-4 LDS, stage-depth 3 --------------
// r24 = r18 (m201 8-phase port, our best schedule family) with ONE change:
// staging depth 1 -> 3 K-tiles. Audit vs the verified bf16 m201 (62% peak;
// identical per-instr MFMA cost and frag bytes to our i8) found one real
// divergence: m201 keeps 3 half-tiles in flight (vmcnt(6), ~2400cyc lead)
// so vmem latency (~900cyc) is never exposed; r18 staged t+1 during t and
// waited with only ~650cyc lead -> ~2x500cyc exposed per 128-K, matching
// the 160us-vs-135us gap. Fix: LDS recut from 2x64KB dbuf to a ring of
// 4 x 32KB (A16+B16 per K-tile, still 128KB). Tile t reads ring[t%4];
// S(t+1..t+3) in flight; end-of-tile VMCNT8 (->4->0 at tail) guarantees
// S(t+1) complete with two full K-tiles (~3000cyc) of lead. Everything
// else r18-identical: 8 waves, wave 128x64, 2 phases/K-tile {8|4 ds_reads,
// 2 stages, BAR, lgkm0, setprio 16-MFMA, BAR}, same swizzles, XCD swizzle.
// Safety: S(t+3) overwrites ring[(t-1)%4], whose reads retired at tile
// t-1's WAITL0 before its final BAR; S(t+3) issues after that BAR.
// Read tile t needs S(t): ensured by end-of-tile t-1 VMCNT8 (outstanding
// {S(t),S(t+1),S(t+2)} -> oldest 4 = S(t) complete), published by BAR.

__device__ __forceinline__ void load_lds16(const void* g, void* l) {
  __builtin_amdgcn_global_load_lds(
      (const __attribute__((address_space(1))) void*)g,
      (__attribute__((address_space(3))) void*)l,
      16, 0, 0);
}

// stage one 8KB unit (128 rows x 64 cols i8) of a [256][64] sub-tile;
// 8 waves x 64 lanes x 16B. u=0,1.
__device__ __forceinline__ void stage_unit(const i8* __restrict__ Gp, int K, int k0,
                                           i8* __restrict__ Tlds, int u, int wave,
                                           int lane) {
  const int base = u * 8192 + wave * 1024;        // physical byte base (wave-uniform)
  const int PA = base + lane * 16;                // this lane's physical bytes
  const int L = PA ^ (((PA >> 7) & 3) << 4);      // logical bytes (involution)
  const int r = L >> 6;                           // tile row (64 i8 per row)
  const int c = L & 63;                           // tile col (16-aligned)
  load_lds16(Gp + (size_t)r * K + k0 + c, Tlds + base);
}

#define BAR __builtin_amdgcn_s_barrier()
#define SGB __builtin_amdgcn_sched_barrier(0)
#define WAITL0 asm volatile("s_waitcnt lgkmcnt(0)" ::: "memory")
#define VMCNT8 asm volatile("s_waitcnt vmcnt(8)" ::: "memory")
#define VMCNT4 asm volatile("s_waitcnt vmcnt(4)" ::: "memory")
#define VMCNT0 asm volatile("s_waitcnt vmcnt(0)" ::: "memory")

// Ring buffer layout: A [256][64] at +0 (16KB), B [256][64] at +16384.
#define READ_A(RC, MIH)                                                         \
  _Pragma("unroll") for (int mi = 0; mi < 4; ++mi)                              \
    Af[mi] = *(const i32x4*)((RC) + abase + ((MIH) * 4 + mi) * 1024);

#define READ_B(RC)                                                              \
  _Pragma("unroll") for (int ni = 0; ni < 4; ++ni)                              \
    Bf[ni] = *(const i32x4*)((RC) + 16384 + bbase + ni * 1024);

#define CLUSTER(MIH)                                                            \
  __builtin_amdgcn_s_setprio(1);                                                \
  _Pragma("unroll") for (int mi = 0; mi < 4; ++mi)                              \
  _Pragma("unroll") for (int ni = 0; ni < 4; ++ni)                              \
    acc[(MIH) * 4 + mi][ni] = __builtin_amdgcn_mfma_i32_16x16x64_i8(            \
        Af[mi], Bf[ni], acc[(MIH) * 4 + mi][ni], 0, 0, 0);                      \
  __builtin_amdgcn_s_setprio(0);

// RC = ring[t%4] (read), RS = ring[(t+3)%4] (stage target, K-tile t+3).
#define DO_TILE(t, RC, RS)                                                      \
  if ((t) < NT) {                                                               \
    const int k3 = ((t) + 3) * 64;                                              \
    const bool st = (t) + 3 < NT;                                               \
    /* ---- p0: mi-lo ---- */                                                   \
    READ_A(RC, 0); READ_B(RC);                                                  \
    if (st) { stage_unit(GA, K, k3, (RS), 0, wave, lane);                       \
              stage_unit(GA, K, k3, (RS), 1, wave, lane); }                     \
    BAR; WAITL0; SGB;                                                           \
    CLUSTER(0); SGB;                                                            \
    BAR;                                                                        \
    /* ---- p1: mi-hi ---- */                                                   \
    READ_A(RC, 1);                                                              \
    if (st) { stage_unit(GB, K, k3, (RS) + 16384, 0, wave, lane);               \
              stage_unit(GB, K, k3, (RS) + 16384, 1, wave, lane); }             \
    BAR; WAITL0; SGB;                                                           \
    CLUSTER(1); SGB;                                                            \
    if (st) { VMCNT8; }                           /* S(t+1) complete */         \
    else if ((t) + 2 < NT) { VMCNT4; }                                          \
    else if ((t) + 1 < NT) { VMCNT0; }                                          \
    BAR;                                          /* publish for tile t+1 */    \
  }

__global__ __launch_bounds__(512, 2) void bingemm256_kernel(
    const i8* __restrict__ A,      // [M][K] i8 (x * 32)
    const i8* __restrict__ B,      // [N][K] i8 sign
    const float* __restrict__ alpha,
    const float* __restrict__ bias,
    float* __restrict__ C,         // [M][N] fp32
    int M, int N, int K) {
  __shared__ i8 SM[4][32768];      // ring of 4 K-tiles x (A 16KB + B 16KB)

  const int tid = threadIdx.x;
  const int lane = tid & 63;
  const int wave = tid >> 6;  // 0..7
  const int wm = wave >> 2;   // 0..1 (128-row slab)
  const int wn = wave & 3;    // 0..3 (64-col slab)
  const int l15 = lane & 15;

  // XCD-aware swizzle (grid divisible by 8 -> simple bijection)
  const int nwg = gridDim.x;
  const int wg = blockIdx.x;
  const int wgid = ((nwg & 7) == 0) ? ((wg & 7) * (nwg >> 3) + (wg >> 3)) : wg;

  const int nbn = N / 256;
  const int tm = wgid / nbn;
  const int tn = wgid % nbn;

  const i8* GA = A + (size_t)tm * 256 * K;
  const i8* GB = B + (size_t)tn * 256 * K;

  // swizzled ds_read byte offsets (row stride 64B, granule 16B):
  // phys k-part = (kq ^ ((row>>1)&3))<<4, (row>>1)&3 == (l15>>1)&3
  const int kq = lane >> 4;                 // 0..3
  const int kph = ((kq ^ ((l15 >> 1) & 3)) << 4);
  const int abase = (wm * 128 + l15) * 64 + kph;   // + (mih*4+mi)*1024
  const int bbase = (wn * 64 + l15) * 64 + kph;    // + ni*1024

  i32x4 acc[8][4];
#pragma unroll
  for (int i = 0; i < 8; ++i)
#pragma unroll
    for (int j = 0; j < 4; ++j)
#pragma unroll
      for (int q = 0; q < 4; ++q) acc[i][j][q] = 0;

  const int NT = K / 64;

  i32x4 Af[4], Bf[4];

  i8* const r0b = &SM[0][0];
  i8* const r1b = &SM[1][0];
  i8* const r2b = &SM[2][0];
  i8* const r3b = &SM[3][0];

  // ---- prologue: stage K-tiles 0,1,2 (depth 3); ensure S(0); publish ----
  stage_unit(GA, K, 0,   r0b,         0, wave, lane);
  stage_unit(GA, K, 0,   r0b,         1, wave, lane);
  stage_unit(GB, K, 0,   r0b + 16384, 0, wave, lane);
  stage_unit(GB, K, 0,   r0b + 16384, 1, wave, lane);
  stage_unit(GA, K, 64,  r1b,         0, wave, lane);
  stage_unit(GA, K, 64,  r1b,         1, wave, lane);
  stage_unit(GB, K, 64,  r1b + 16384, 0, wave, lane);
  stage_unit(GB, K, 64,  r1b + 16384, 1, wave, lane);
  stage_unit(GA, K, 128, r2b,         0, wave, lane);
  stage_unit(GA, K, 128, r2b,         1, wave, lane);
  stage_unit(GB, K, 128, r2b + 16384, 0, wave, lane);
  stage_unit(GB, K, 128, r2b + 16384, 1, wave, lane);
  VMCNT8;   // S(0) complete; S(1),S(2) in flight
  BAR;

  for (int t = 0; t < NT; t += 4) {
    DO_TILE(t,     r0b, r3b);
    DO_TILE(t + 1, r1b, r0b);
    DO_TILE(t + 2, r2b, r1b);
    DO_TILE(t + 3, r3b, r2b);
  }

  // ---- epilogue: C = acc * alpha[col]/32 + bias[col] (nontemporal) ----
  const int r0 = tm * 256 + wm * 128 + ((lane >> 4) << 2);
  const int c0 = tn * 256 + wn * 64 + l15;
#pragma unroll
  for (int an = 0; an < 4; ++an) {
    const int col = c0 + an * 16;
    const float al = alpha[col] * INV_XSCALE;
    const float bi = bias[col];
#pragma unroll
    for (int am = 0; am < 8; ++am) {
#pragma unroll
      for (int j = 0; j < 4; ++j) {
        __builtin_nontemporal_store((float)acc[am][an][j] * al + bi,
                                    &C[(size_t)(r0 + am * 16 + j) * N + col]);
      }
    }
  }
}

// ---------------- fallback (insurance: ws too small / bad dims) ----------------

__global__ __launch_bounds__(256) void naive_kernel(
    const float* __restrict__ x, const float* __restrict__ w,
    const float* __restrict__ alpha, const float* __restrict__ bias,
    float* __restrict__ out, int M, int N, int K) {
  long idx = (long)blockIdx.x * blockDim.x + threadIdx.x;
  const long total = (long)M * N;
  const long stride = (long)gridDim.x * blockDim.x;
  for (; idx < total; idx += stride) {
    const int m = (int)(idx / N);
    const int n = (int)(idx % N);
    const float* xr = x + (size_t)m * K;
    const float* wr = w + (size_t)n * K;
    float s = 0.0f;
    for (int k = 0; k < K; ++k) {
      const float wv = wr[k];
      const float sg = (wv > 0.0f) ? 1.0f : ((wv < 0.0f) ? -1.0f : 0.0f);
      s += xr[k] * sg;
    }
    out[idx] = s * alpha[n] + bias[n];
  }
}

// ---------------- launcher ----------------

extern "C" void kernel_launch(void* const* d_in, const int* in_sizes, int n_in,
                              void* d_out, int out_size, void* d_ws, size_t ws_size,
                              hipStream_t stream) {
  const float* x = (const float*)d_in[0];
  const float* w = (const float*)d_in[1];
  const float* alpha = (const float*)d_in[2];
  const float* bias = (const float*)d_in[3];
  float* out = (float*)d_out;

  const int OUT = in_sizes[3];                // bias length
  const int IN = in_sizes[1] / OUT;           // weight is [OUT][IN]
  const int M = in_sizes[0] / IN;             // x is [B][IN]
  const int N = OUT, K = IN;

  const size_t xbytes = (size_t)M * K;        // i8
  const size_t wbytes = (size_t)N * K;        // i8
  // NT = K/64 must be >= 4 and divisible by 4 (ring-4 unroll).
  const bool ok = (ws_size >= xbytes + wbytes) &&
                  (M % 256 == 0) && (N % 256 == 0) && (K % 256 == 0) &&
                  (K >= 256);

  if (!ok) {
    naive_kernel<<<2048, 256, 0, stream>>>(x, w, alpha, bias, out, M, N, K);
    return;
  }

  i8* xb = (i8*)d_ws;
  i8* wb = xb + xbytes;

  cvt_x_kernel<<<2048, 256, 0, stream>>>(x, (i32x4*)xb, (int)((size_t)M * K / 16));
  cvt_w_kernel<<<2048, 256, 0, stream>>>(w, (i32x4*)wb, (int)((size_t)N * K / 16));

  const int grid = (M / 256) * (N / 256);
  bingemm256_kernel<<<grid, 512, 0, stream>>>(xb, wb, alpha, bias, out, M, N, K);
}